// Round 5
// baseline (835.671 us; speedup 1.0000x reference)
//
#include <hip/hip_runtime.h>
#include <math.h>

#define BSZ 16
#define NTOK 50625
#define NLAYERS 6
#define NBOT 26
#define NTILE 3165                  // ceil(50625/16), last tile has 1 token

// persistent kernel: 512 blocks x 256 thr = 2048 waves, co-resident at
// 2 blocks/CU. Residual X lives in 100 AGPRs per thread via explicit
// v_accvgpr_write/read inline asm ("a" register class).
// WHY: gfx950 splits the unified 256-reg/wave budget 128 VGPR + 128 AGPR
// when MFMA is present (R2-R4: VGPR_Count pinned at 128 under three
// different occupancy attributes, ~115MB scratch traffic). The AGPR half
// was idle; X goes there, arch half holds the working set.
// 32 blocks per batch; sync is PER-BATCH (acc[b] touched only by batch b).
#define PBLK 256
#define PGRID 512
#define WPB 4
#define NWAVE (PGRID*WPB)
#define WPBATCH (NWAVE/BSZ)         // 128 waves per batch
#define BPB (PGRID/BSZ)             // 32 blocks per batch
#define TPWAVE 25                   // 128*25 = 3200 >= 3165 tiles

#define ACC_PER_LAYER (BSZ*8*5)     // 640 floats
#define ACC_FLOATS (2*NLAYERS*ACC_PER_LAYER)
#define BAR_OFF ((size_t)ACC_FLOATS*4)      // 30720; 16 counters * 128B = 2048
#define FRAG_OFF ((size_t)32768)
#define C2_OFF (FRAG_OFF + (size_t)98*64*8)

typedef float f32x4 __attribute__((ext_vector_type(4)));
typedef _Float16 half4 __attribute__((ext_vector_type(4)));

#define MFMA(A,B,C) __builtin_amdgcn_mfma_f32_16x16x16f16((A),(B),(C),0,0,0)

#define TILES(OP) OP(0) OP(1) OP(2) OP(3) OP(4) OP(5) OP(6) OP(7) OP(8) OP(9) \
  OP(10) OP(11) OP(12) OP(13) OP(14) OP(15) OP(16) OP(17) OP(18) OP(19) \
  OP(20) OP(21) OP(22) OP(23) OP(24)

// X tile i -> 4 floats pinned to AGPR class
#define XDECL(i) float ax##i##_0, ax##i##_1, ax##i##_2, ax##i##_3;

#define XSTORE(i, xx) { \
    asm("v_accvgpr_write_b32 %0, %1" : "=a"(ax##i##_0) : "v"((xx)[0])); \
    asm("v_accvgpr_write_b32 %0, %1" : "=a"(ax##i##_1) : "v"((xx)[1])); \
    asm("v_accvgpr_write_b32 %0, %1" : "=a"(ax##i##_2) : "v"((xx)[2])); \
    asm("v_accvgpr_write_b32 %0, %1" : "=a"(ax##i##_3) : "v"((xx)[3])); }

#define XLOAD(i, xx) { \
    float r0_, r1_, r2_, r3_; \
    asm("v_accvgpr_read_b32 %0, %1" : "=v"(r0_) : "a"(ax##i##_0)); \
    asm("v_accvgpr_read_b32 %0, %1" : "=v"(r1_) : "a"(ax##i##_1)); \
    asm("v_accvgpr_read_b32 %0, %1" : "=v"(r2_) : "a"(ax##i##_2)); \
    asm("v_accvgpr_read_b32 %0, %1" : "=v"(r3_) : "a"(ax##i##_3)); \
    (xx)[0]=r0_; (xx)[1]=r1_; (xx)[2]=r2_; (xx)[3]=r3_; }

__device__ __forceinline__ unsigned short h2u(_Float16 h) {
    union { _Float16 h; unsigned short u; } x; x.h = h; return x.u;
}

__device__ __forceinline__ half4 cvt4(f32x4 v) {
    half4 r; r[0]=(_Float16)v[0]; r[1]=(_Float16)v[1];
    r[2]=(_Float16)v[2]; r[3]=(_Float16)v[3]; return r;
}

// erf-series gelu in packed fp16 (|z| <= ~0.5 here)
__device__ __forceinline__ half4 gelu4(half4 z) {
    const _Float16 cA = (_Float16)0.35355339f;
    const _Float16 c0 = (_Float16)1.1283792f;
    const _Float16 c1 = (_Float16)-0.18806319f;
    const _Float16 c2 = (_Float16)0.028209479f;
    const _Float16 ch = (_Float16)0.5f;
    half4 z2 = z*z;
    half4 p  = z2*c2 + c1;
    p = z2*p + c0;
    return z*ch + (z2*cA)*p;
}

// cubic exp: logits |l| <= ~0.05 -> rel err < 1e-5 on softmax weights
__device__ __forceinline__ float exp3(float l) {
    return fmaf(l, fmaf(l, fmaf(l, 0.16666667f, 0.5f), 1.0f), 1.0f);
}

// LN over 16 dims: 4 in-lane (rows 4*quad+i) x 4 quads (xor 16, 32)
__device__ __forceinline__ f32x4 ln16v(f32x4 x, f32x4 g, f32x4 bb) {
    float s = x[0]+x[1]+x[2]+x[3];
    s += __shfl_xor(s, 16); s += __shfl_xor(s, 32);
    float m = s * 0.0625f;
    f32x4 t = x - m;
    float v = t[0]*t[0]+t[1]*t[1]+t[2]*t[2]+t[3]*t[3];
    v += __shfl_xor(v, 16); v += __shfl_xor(v, 32);
    float r = rsqrtf(v * 0.0625f + 1e-5f);
    return t * r * g + bb;
}

// coherent (agent-scope) load: acc values are produced by device-scope
// atomics on other XCDs; bypass potentially-stale local caches.
__device__ __forceinline__ float cohload(const float* p) {
    return __hip_atomic_load(p, __ATOMIC_RELAXED, __HIP_MEMORY_SCOPE_AGENT);
}

__device__ __forceinline__ void load_g(const float* accB, int quad, f32x4* gA, f32x4* gB) {
    const float* a = accB + quad*5;
    float i0 = 1.0f / cohload(a+0);
    (*gA)[0]=cohload(a+1)*i0; (*gA)[1]=cohload(a+2)*i0;
    (*gA)[2]=cohload(a+3)*i0; (*gA)[3]=cohload(a+4)*i0;
    const float* a2 = accB + (quad+4)*5;
    float i1 = 1.0f / cohload(a2+0);
    (*gB)[0]=cohload(a2+1)*i1; (*gB)[1]=cohload(a2+2)*i1;
    (*gB)[2]=cohload(a2+3)*i1; (*gB)[3]=cohload(a2+4)*i1;
}

__device__ __forceinline__ void accum_partials(
    float pwA, f32x4 paA, float pwB, f32x4 paB,
    float* red, float* accB)
{
    const int lane = threadIdx.x & 63, wv = threadIdx.x >> 6;
    const int col = lane & 15, quad = lane >> 4;
#pragma unroll
    for (int off = 1; off < 16; off <<= 1) {
        pwA += __shfl_xor(pwA, off); pwB += __shfl_xor(pwB, off);
#pragma unroll
        for (int i = 0; i < 4; i++) {
            paA[i] += __shfl_xor(paA[i], off);
            paB[i] += __shfl_xor(paB[i], off);
        }
    }
    if (col == 0) {
        red[(quad*5+0)*4+wv] = pwA; red[((quad+4)*5+0)*4+wv] = pwB;
#pragma unroll
        for (int i = 0; i < 4; i++) {
            red[(quad*5+1+i)*4+wv] = paA[i];
            red[((quad+4)*5+1+i)*4+wv] = paB[i];
        }
    }
    __syncthreads();
    const int t = threadIdx.x;
    if (t < 40)
        atomicAdd(&accB[t], red[t*4+0]+red[t*4+1]+red[t*4+2]+red[t*4+3]);
}

// per-batch barrier over BPB blocks: monotone counter, release add + acquire poll.
__device__ __forceinline__ void gbar(unsigned* mybar, unsigned target) {
    __syncthreads();
    if (threadIdx.x == 0) {
        __hip_atomic_fetch_add(mybar, 1u, __ATOMIC_ACQ_REL, __HIP_MEMORY_SCOPE_AGENT);
        while (__hip_atomic_load(mybar, __ATOMIC_ACQUIRE, __HIP_MEMORY_SCOPE_AGENT) < target)
            __builtin_amdgcn_s_sleep(4);
    }
    __syncthreads();
}

// ---------------------------------------------------------------------------
// kPrep (parallel, 25 blocks): fp16 A-fragments. Per-layer frag ids:
//  0 M1=Wo@Wq  1 Cperm  2,3 Wv  4,5 Wk  6,7 Wq  8..11 FF1  12..15 FF2
// ids 96,97: W_emb K-tiles.  c2[l][od] = sum_c Wo[c][od]*b_r[c&3] + b_o[od].
// ---------------------------------------------------------------------------
__global__ __launch_bounds__(256) void kPrep(
    const float* __restrict__ Wqkv, const float* __restrict__ Wo,
    const float* __restrict__ Wr, const float* __restrict__ W1,
    const float* __restrict__ W2, const float* __restrict__ W_emb,
    const float* __restrict__ br, const float* __restrict__ bo,
    unsigned short* __restrict__ frag, float* __restrict__ c2)
{
    const int it = blockIdx.x*256 + (int)threadIdx.x;
    if (it < 98*64) {
        const int lane = it & 63, fid = it >> 6;
        const int m = lane & 15, q = lane >> 4;
        for (int j = 0; j < 4; j++) {
            const int k = q*4 + j;
            float w = 0.f;
            if (fid < 96) {
                const int layer = fid >> 4, f = fid & 15;
                const float* Wq_ = Wqkv + layer*1536;
                if (f == 0) {
                    for (int c = 0; c < 32; c++)
                        w += Wo[layer*512 + c*16 + m] * Wq_[k*96 + c];
                } else if (f == 1) {
                    const int h = q + ((j >= 2) ? 4 : 0), j2 = j & 1;
                    for (int d = 0; d < 4; d++)
                        w += Wo[layer*512 + (h*4+d)*16 + m] * Wr[layer*8 + j2*4 + d];
                } else if (f < 4)  w = Wq_[k*96 + 64 + (f-2)*16 + m];
                else if (f < 6)    w = Wq_[k*96 + 32 + (f-4)*16 + m];
                else if (f < 8)    w = Wq_[k*96 + (f-6)*16 + m];
                else if (f < 12)   w = W1[layer*1024 + k*64 + (f-8)*16 + m];
                else               w = W2[layer*1024 + ((f-12)*16 + k)*16 + m];
            } else {
                const int c = (fid-96)*16 + k;
                w = (c < NBOT) ? W_emb[c*16 + m] : 0.f;
            }
            frag[(size_t)it*4 + j] = h2u((_Float16)w);
        }
    }
    if (blockIdx.x == 0 && threadIdx.x < 96) {
        const int layer = threadIdx.x >> 4, od = threadIdx.x & 15;
        float s = bo[layer*16 + od];
        for (int c = 0; c < 32; c++)
            s += Wo[layer*512 + c*16 + od] * br[layer*4 + (c & 3)];
        c2[threadIdx.x] = s;
    }
}

// ---------------------------------------------------------------------------
// kMain: persistent kernel. X in 100 AGPRs/thread; Y recomputed from X.
// 12 per-batch barriers (2/layer, from the sequential q->k softmax reductions).
// ---------------------------------------------------------------------------
__global__
__attribute__((amdgpu_flat_work_group_size(PBLK, PBLK), amdgpu_waves_per_eu(2, 2)))
void kMain(
    const float* __restrict__ corr, const unsigned short* __restrict__ frag,
    const float* __restrict__ b_emb, const float* __restrict__ ln1_g,
    const float* __restrict__ ln1_b, const float* __restrict__ ln2_g,
    const float* __restrict__ ln2_b, const float* __restrict__ w_qlog,
    const float* __restrict__ w_klog, const float* __restrict__ c2,
    const float* __restrict__ b_ff1, const float* __restrict__ b_ff2,
    const float* __restrict__ W_out, const float* __restrict__ b_out,
    float* __restrict__ acc, unsigned* __restrict__ bar,
    float* __restrict__ out)
{
    __shared__ float red[160];

    const int lane = threadIdx.x & 63;
    const int col = lane & 15, quad = lane >> 4;
    const int gw = blockIdx.x*WPB + (int)(threadIdx.x >> 6);  // 0..2047
    const int b  = gw >> 7;                  // batch (block-uniform: 32 blks/batch)
    const int lw = gw & (WPBATCH-1);         // wave within batch
    const half4* F = (const half4*)frag;
    const float sgn = (col & 1) ? -1.f : 1.f;
    const f32x4 Z = {0,0,0,0};
    float* accQ = acc;
    float* accK = acc + NLAYERS*ACC_PER_LAYER;
    unsigned* mybar = bar + b*32;            // 128B-spaced per-batch counter
    const f32x4 wo4 = *(const f32x4*)(W_out + 4*quad);
    const float bout0 = b_out[0];

    TILES(XDECL)                             // 100 AGPR-class floats

    // ---- embed: relu(corr)@W_emb + b_emb -> AGPRs; layer-0 q-partials
    {
        const half4 fE0 = F[96*64 + lane];
        const half4 fE1 = F[97*64 + lane];
        const half4 fQ0 = F[6*64 + lane];
        const half4 fQ1 = F[7*64 + lane];
        const f32x4 be4 = *(const f32x4*)(b_emb + 4*quad);
        const f32x4 g1  = *(const f32x4*)(ln1_g + 4*quad);
        const f32x4 b1  = *(const f32x4*)(ln1_b + 4*quad);
        const float wq0 = w_qlog[0], wq1 = w_qlog[1], wq2 = w_qlog[2], wq3 = w_qlog[3];
        // tile-invariant row pointers (8 rows this thread reads)
        const float* cr0 = corr + ((size_t)b*NBOT + (4*quad+0))*NTOK;
        const float* cr1 = corr + ((size_t)b*NBOT + (4*quad+1))*NTOK;
        const float* cr2 = corr + ((size_t)b*NBOT + (4*quad+2))*NTOK;
        const float* cr3 = corr + ((size_t)b*NBOT + (4*quad+3))*NTOK;
        const int d0 = (16+4*quad+0 < NBOT) ? 16+4*quad+0 : NBOT-1;
        const int d1 = (16+4*quad+1 < NBOT) ? 16+4*quad+1 : NBOT-1;
        const int d2 = (16+4*quad+2 < NBOT) ? 16+4*quad+2 : NBOT-1;
        const int d3 = (16+4*quad+3 < NBOT) ? 16+4*quad+3 : NBOT-1;
        const float* cs0 = corr + ((size_t)b*NBOT + d0)*NTOK;
        const float* cs1 = corr + ((size_t)b*NBOT + d1)*NTOK;
        const float* cs2 = corr + ((size_t)b*NBOT + d2)*NTOK;
        const float* cs3 = corr + ((size_t)b*NBOT + d3)*NTOK;
        float pwA = 0.f, pwB = 0.f;
        f32x4 paA = Z, paB = Z;

#define EMB(i) { \
        const int lt  = lw*TPWAVE + i; \
        const int ltc = (lt < NTILE) ? lt : (NTILE-1); \
        const int n0  = ltc*16; \
        const int valid = (lt < NTILE) && ((n0 + col) < NTOK); \
        const int nn = ((n0 + col) < NTOK) ? (n0 + col) : (NTOK - 1); \
        half4 ch0, ch1; \
        ch0[0] = (_Float16)fmaxf(cr0[nn], 0.f); \
        ch0[1] = (_Float16)fmaxf(cr1[nn], 0.f); \
        ch0[2] = (_Float16)fmaxf(cr2[nn], 0.f); \
        ch0[3] = (_Float16)fmaxf(cr3[nn], 0.f); \
        ch1[0] = (_Float16)fmaxf(cs0[nn], 0.f); \
        ch1[1] = (_Float16)fmaxf(cs1[nn], 0.f); \
        ch1[2] = (_Float16)fmaxf(cs2[nn], 0.f); \
        ch1[3] = (_Float16)fmaxf(cs3[nn], 0.f); \
        f32x4 xx = be4; \
        xx = MFMA(fE0, ch0, xx); \
        xx = MFMA(fE1, ch1, xx); \
        XSTORE(i, xx) \
        f32x4 y = ln16v(xx, g1, b1); \
        half4 yh = cvt4(y); \
        f32x4 q0 = MFMA(fQ0, yh, Z); \
        f32x4 q1 = MFMA(fQ1, yh, Z); \
        { float l = 0.5f*(q0[0]*wq0 + q0[1]*wq1 + q0[2]*wq2 + q0[3]*wq3); \
          float e = valid ? exp3(l) : 0.f; \
          pwA += e; paA += (e*sgn) * q0; } \
        { float l = 0.5f*(q1[0]*wq0 + q1[1]*wq1 + q1[2]*wq2 + q1[3]*wq3); \
          float e = valid ? exp3(l) : 0.f; \
          pwB += e; paB += (e*sgn) * q1; } }
        TILES(EMB)
#undef EMB
        accum_partials(pwA, paA, pwB, paB, red, accQ + b*40);
    }

    unsigned bstep = 1;
    for (int layer = 0; layer < NLAYERS; layer++) {
        const size_t fb = (size_t)layer*16*64;
        const int last = (layer == NLAYERS-1);
        const f32x4 g1c = *(const f32x4*)(ln1_g + layer*16 + 4*quad);
        const f32x4 b1c = *(const f32x4*)(ln1_b + layer*16 + 4*quad);

        gbar(mybar, BPB*bstep); bstep++;     // accQ[layer][b] complete

        // ---- phase B: k-projection + k-phase partials (Y recomputed from X)
        {
            const half4 fK0 = F[fb + 4*64 + lane];
            const half4 fK1 = F[fb + 5*64 + lane];
            f32x4 gqA, gqB; load_g(accQ + layer*ACC_PER_LAYER + b*40, quad, &gqA, &gqB);
            const float wk0 = w_klog[layer*2+0], wk1 = w_klog[layer*2+1];
            float pwA = 0.f, pwB = 0.f;
            f32x4 paA = Z, paB = Z;

#define PHB(i) { \
            const int lt = lw*TPWAVE + i; \
            const int valid = (lt < NTILE) && ((lt*16 + col) < NTOK); \
            f32x4 xx; XLOAD(i, xx) \
            f32x4 y = ln16v(xx, g1c, b1c); \
            half4 yh = cvt4(y); \
            f32x4 k0 = MFMA(fK0, yh, Z); \
            f32x4 k1 = MFMA(fK1, yh, Z); \
            { float a0 = k0[0]*gqA[0] + k0[1]*gqA[1]; \
              float a1 = k0[2]*gqA[2] + k0[3]*gqA[3]; \
              float e = valid ? exp3(0.5f*(a0*wk0 + a1*wk1)) : 0.f; \
              pwA += e; paA += (e*sgn) * k0; } \
            { float a0 = k1[0]*gqB[0] + k1[1]*gqB[1]; \
              float a1 = k1[2]*gqB[2] + k1[3]*gqB[3]; \
              float e = valid ? exp3(0.5f*(a0*wk0 + a1*wk1)) : 0.f; \
              pwB += e; paB += (e*sgn) * k1; } }
            TILES(PHB)
#undef PHB
            accum_partials(pwA, paA, pwB, paB, red, accK + layer*ACC_PER_LAYER + b*40);
        }

        gbar(mybar, BPB*bstep); bstep++;     // accK[layer][b] complete

        // ---- phase C: attn delta -> xn -> LN2 -> FF -> xo; next-layer q-partials
        {
            const int nl = last ? layer : layer + 1;
            const size_t nb2 = (size_t)nl*16*64;
            const half4 fM1 = F[fb + 0*64 + lane];
            const half4 fCp = F[fb + 1*64 + lane];
            const half4 fV0 = F[fb + 2*64 + lane];
            const half4 fV1 = F[fb + 3*64 + lane];
            const half4 fF1_0 = F[fb + 8*64 + lane];
            const half4 fF1_1 = F[fb + 9*64 + lane];
            const half4 fF1_2 = F[fb + 10*64 + lane];
            const half4 fF1_3 = F[fb + 11*64 + lane];
            const half4 fF2_0 = F[fb + 12*64 + lane];
            const half4 fF2_1 = F[fb + 13*64 + lane];
            const half4 fF2_2 = F[fb + 14*64 + lane];
            const half4 fF2_3 = F[fb + 15*64 + lane];
            const half4 fQ0 = F[nb2 + 6*64 + lane];
            const half4 fQ1 = F[nb2 + 7*64 + lane];
            const f32x4 c2q  = *(const f32x4*)(c2 + layer*16 + 4*quad);
            const f32x4 g2   = *(const f32x4*)(ln2_g + layer*16 + 4*quad);
            const f32x4 b2   = *(const f32x4*)(ln2_b + layer*16 + 4*quad);
            const f32x4 g1n  = *(const f32x4*)(ln1_g + nl*16 + 4*quad);
            const f32x4 b1n  = *(const f32x4*)(ln1_b + nl*16 + 4*quad);
            const f32x4 bf2q = *(const f32x4*)(b_ff2 + layer*16 + 4*quad);
            const half4 bf1h0 = cvt4(*(const f32x4*)(b_ff1 + layer*64 +  0 + 4*quad));
            const half4 bf1h1 = cvt4(*(const f32x4*)(b_ff1 + layer*64 + 16 + 4*quad));
            const half4 bf1h2 = cvt4(*(const f32x4*)(b_ff1 + layer*64 + 32 + 4*quad));
            const half4 bf1h3 = cvt4(*(const f32x4*)(b_ff1 + layer*64 + 48 + 4*quad));
            f32x4 gkA, gkB; load_g(accK + layer*ACC_PER_LAYER + b*40, quad, &gkA, &gkB);
            const float wq0 = w_qlog[nl*4+0], wq1 = w_qlog[nl*4+1];
            const float wq2 = w_qlog[nl*4+2], wq3 = w_qlog[nl*4+3];
            float pwA = 0.f, pwB = 0.f;
            f32x4 paA = Z, paB = Z;

#define PHC(i) { \
            const int lt  = lw*TPWAVE + i; \
            const int ltc = (lt < NTILE) ? lt : (NTILE-1); \
            const int n0  = ltc*16; \
            const int valid = (lt < NTILE) && ((n0 + col) < NTOK); \
            f32x4 xv; XLOAD(i, xv) \
            f32x4 y1 = ln16v(xv, g1c, b1c); \
            half4 yh = cvt4(y1); \
            f32x4 d = c2q; \
            d = MFMA(fM1, yh, d); \
            f32x4 v0 = MFMA(fV0, yh, Z); \
            f32x4 v1 = MFMA(fV1, yh, Z); \
            f32x4 u; \
            u[0] = v0[0]*gkA[0] + v0[1]*gkA[1]; \
            u[1] = v0[2]*gkA[2] + v0[3]*gkA[3]; \
            u[2] = v1[0]*gkB[0] + v1[1]*gkB[1]; \
            u[3] = v1[2]*gkB[2] + v1[3]*gkB[3]; \
            half4 uh = cvt4(u); \
            d = MFMA(fCp, uh, d); \
            f32x4 xn = xv + d; \
            f32x4 y2 = ln16v(xn, g2, b2); \
            half4 y2h = cvt4(y2); \
            f32x4 z0 = MFMA(fF1_0, y2h, Z); \
            f32x4 z1 = MFMA(fF1_1, y2h, Z); \
            f32x4 z2 = MFMA(fF1_2, y2h, Z); \
            f32x4 z3 = MFMA(fF1_3, y2h, Z); \
            half4 h0 = gelu4(cvt4(z0) + bf1h0); \
            half4 h1 = gelu4(cvt4(z1) + bf1h1); \
            half4 h2 = gelu4(cvt4(z2) + bf1h2); \
            half4 h3 = gelu4(cvt4(z3) + bf1h3); \
            f32x4 xo = xn + bf2q; \
            xo = MFMA(fF2_0, h0, xo); \
            xo = MFMA(fF2_1, h1, xo); \
            f32x4 xb = MFMA(fF2_2, h2, Z); \
            xb = MFMA(fF2_3, h3, xb); \
            xo = xo + xb; \
            XSTORE(i, xo) \
            if (!last) { \
                f32x4 yn = ln16v(xo, g1n, b1n); \
                half4 ynh = cvt4(yn); \
                f32x4 q0 = MFMA(fQ0, ynh, Z); \
                f32x4 q1 = MFMA(fQ1, ynh, Z); \
                { float l = 0.5f*(q0[0]*wq0 + q0[1]*wq1 + q0[2]*wq2 + q0[3]*wq3); \
                  float e = valid ? exp3(l) : 0.f; \
                  pwA += e; paA += (e*sgn) * q0; } \
                { float l = 0.5f*(q1[0]*wq0 + q1[1]*wq1 + q1[2]*wq2 + q1[3]*wq3); \
                  float e = valid ? exp3(l) : 0.f; \
                  pwB += e; paB += (e*sgn) * q1; } \
            } else { \
                float s = xo[0]*wo4[0] + xo[1]*wo4[1] + xo[2]*wo4[2] + xo[3]*wo4[3]; \
                s += __shfl_xor(s, 16); s += __shfl_xor(s, 32); \
                if (quad == 0 && valid) out[(size_t)b*NTOK + n0 + col] = s + bout0; \
            } }
            TILES(PHC)
#undef PHC
            if (!last)
                accum_partials(pwA, paA, pwB, paB, red, accQ + (layer+1)*ACC_PER_LAYER + b*40);
        }
    }
}

extern "C" void kernel_launch(void* const* d_in, const int* in_sizes, int n_in,
                              void* d_out, int out_size, void* d_ws, size_t ws_size,
                              hipStream_t stream) {
    const float* corr  = (const float*)d_in[0];
    const float* W_emb = (const float*)d_in[1];
    const float* b_emb = (const float*)d_in[2];
    const float* ln1_g = (const float*)d_in[3];
    const float* ln1_b = (const float*)d_in[4];
    const float* W_qkv = (const float*)d_in[5];
    const float* w_qlog= (const float*)d_in[6];
    const float* w_klog= (const float*)d_in[7];
    const float* W_r   = (const float*)d_in[8];
    const float* b_r   = (const float*)d_in[9];
    const float* W_o   = (const float*)d_in[10];
    const float* b_o   = (const float*)d_in[11];
    const float* ln2_g = (const float*)d_in[12];
    const float* ln2_b = (const float*)d_in[13];
    const float* W_ff1 = (const float*)d_in[14];
    const float* b_ff1 = (const float*)d_in[15];
    const float* W_ff2 = (const float*)d_in[16];
    const float* b_ff2 = (const float*)d_in[17];
    const float* W_out = (const float*)d_in[18];
    const float* b_out = (const float*)d_in[19];

    float* acc = (float*)d_ws;
    unsigned* bar = (unsigned*)((char*)d_ws + BAR_OFF);
    unsigned short* frag = (unsigned short*)((char*)d_ws + FRAG_OFF);
    float* c2 = (float*)((char*)d_ws + C2_OFF);

    // zero acc (30720 B) + 16 per-batch barrier counters (2048 B) in one memset
    hipMemsetAsync(d_ws, 0, 32768, stream);
    kPrep<<<25, 256, 0, stream>>>(W_qkv, W_o, W_r, W_ff1, W_ff2, W_emb, b_r, b_o,
                                  frag, c2);

    kMain<<<dim3(PGRID), dim3(PBLK), 0, stream>>>(
        corr, frag, b_emb, ln1_g, ln1_b, ln2_g, ln2_b, w_qlog, w_klog, c2,
        b_ff1, b_ff2, W_out, b_out, acc, bar, (float*)d_out);
}

// Round 6
// 723.012 us; speedup vs baseline: 1.1558x; 1.1558x over previous
//
#include <hip/hip_runtime.h>
#include <math.h>

#define BSZ 16
#define NTOK 50625
#define NLAYERS 6
#define NBOT 26
#define NTILE 3165                  // ceil(50625/16), last tile has 1 token

// persistent kernel: 512 blocks x 256 thr = 2048 waves, co-resident at
// 2 blocks/CU. Residual X lives in 25 NAMED f32x4 registers per thread.
// R2-R5 forensics: backend allocates for 4 waves/EU (128 unified regs) and
// IGNORES launch_bounds(256,2) AND amdgpu_waves_per_eu(2,2) -> ~200-reg live
// set spills to scratch (115-460MB HBM). Proof: spills went to MEMORY, never
// to AGPRs (backend prefers AGPR spill slots when free), and R5's explicit
// "a"-class regs ALSO got scratch slots => zero free AGPRs => total budget
// was 128. Fix: amdgpu_num_vgpr(256) sets the allocation target directly,
// bypassing the waves-per-eu clamp.
// 32 blocks per batch; sync is PER-BATCH (acc[b] touched only by batch b).
#define PBLK 256
#define PGRID 512
#define WPB 4
#define NWAVE (PGRID*WPB)
#define WPBATCH (NWAVE/BSZ)         // 128 waves per batch
#define BPB (PGRID/BSZ)             // 32 blocks per batch
#define TPWAVE 25                   // 128*25 = 3200 >= 3165 tiles

#define ACC_PER_LAYER (BSZ*8*5)     // 640 floats
#define ACC_FLOATS (2*NLAYERS*ACC_PER_LAYER)
#define BAR_OFF ((size_t)ACC_FLOATS*4)      // 30720; 16 counters * 128B = 2048
#define FRAG_OFF ((size_t)32768)
#define C2_OFF (FRAG_OFF + (size_t)98*64*8)

typedef float f32x4 __attribute__((ext_vector_type(4)));
typedef _Float16 half4 __attribute__((ext_vector_type(4)));

#define MFMA(A,B,C) __builtin_amdgcn_mfma_f32_16x16x16f16((A),(B),(C),0,0,0)

#define TILES(OP) OP(0) OP(1) OP(2) OP(3) OP(4) OP(5) OP(6) OP(7) OP(8) OP(9) \
  OP(10) OP(11) OP(12) OP(13) OP(14) OP(15) OP(16) OP(17) OP(18) OP(19) \
  OP(20) OP(21) OP(22) OP(23) OP(24)

__device__ __forceinline__ unsigned short h2u(_Float16 h) {
    union { _Float16 h; unsigned short u; } x; x.h = h; return x.u;
}

__device__ __forceinline__ half4 cvt4(f32x4 v) {
    half4 r; r[0]=(_Float16)v[0]; r[1]=(_Float16)v[1];
    r[2]=(_Float16)v[2]; r[3]=(_Float16)v[3]; return r;
}

// erf-series gelu in packed fp16 (|z| <= ~0.5 here)
__device__ __forceinline__ half4 gelu4(half4 z) {
    const _Float16 cA = (_Float16)0.35355339f;
    const _Float16 c0 = (_Float16)1.1283792f;
    const _Float16 c1 = (_Float16)-0.18806319f;
    const _Float16 c2 = (_Float16)0.028209479f;
    const _Float16 ch = (_Float16)0.5f;
    half4 z2 = z*z;
    half4 p  = z2*c2 + c1;
    p = z2*p + c0;
    return z*ch + (z2*cA)*p;
}

// cubic exp: logits |l| <= ~0.05 -> rel err < 1e-5 on softmax weights
__device__ __forceinline__ float exp3(float l) {
    return fmaf(l, fmaf(l, fmaf(l, 0.16666667f, 0.5f), 1.0f), 1.0f);
}

// LN over 16 dims: 4 in-lane (rows 4*quad+i) x 4 quads (xor 16, 32)
__device__ __forceinline__ f32x4 ln16v(f32x4 x, f32x4 g, f32x4 bb) {
    float s = x[0]+x[1]+x[2]+x[3];
    s += __shfl_xor(s, 16); s += __shfl_xor(s, 32);
    float m = s * 0.0625f;
    f32x4 t = x - m;
    float v = t[0]*t[0]+t[1]*t[1]+t[2]*t[2]+t[3]*t[3];
    v += __shfl_xor(v, 16); v += __shfl_xor(v, 32);
    float r = rsqrtf(v * 0.0625f + 1e-5f);
    return t * r * g + bb;
}

// coherent (agent-scope) load: acc values are produced by device-scope
// atomics on other XCDs; bypass potentially-stale local caches.
__device__ __forceinline__ float cohload(const float* p) {
    return __hip_atomic_load(p, __ATOMIC_RELAXED, __HIP_MEMORY_SCOPE_AGENT);
}

__device__ __forceinline__ void load_g(const float* accB, int quad, f32x4* gA, f32x4* gB) {
    const float* a = accB + quad*5;
    float i0 = 1.0f / cohload(a+0);
    (*gA)[0]=cohload(a+1)*i0; (*gA)[1]=cohload(a+2)*i0;
    (*gA)[2]=cohload(a+3)*i0; (*gA)[3]=cohload(a+4)*i0;
    const float* a2 = accB + (quad+4)*5;
    float i1 = 1.0f / cohload(a2+0);
    (*gB)[0]=cohload(a2+1)*i1; (*gB)[1]=cohload(a2+2)*i1;
    (*gB)[2]=cohload(a2+3)*i1; (*gB)[3]=cohload(a2+4)*i1;
}

__device__ __forceinline__ void accum_partials(
    float pwA, f32x4 paA, float pwB, f32x4 paB,
    float* red, float* accB)
{
    const int lane = threadIdx.x & 63, wv = threadIdx.x >> 6;
    const int col = lane & 15, quad = lane >> 4;
#pragma unroll
    for (int off = 1; off < 16; off <<= 1) {
        pwA += __shfl_xor(pwA, off); pwB += __shfl_xor(pwB, off);
#pragma unroll
        for (int i = 0; i < 4; i++) {
            paA[i] += __shfl_xor(paA[i], off);
            paB[i] += __shfl_xor(paB[i], off);
        }
    }
    if (col == 0) {
        red[(quad*5+0)*4+wv] = pwA; red[((quad+4)*5+0)*4+wv] = pwB;
#pragma unroll
        for (int i = 0; i < 4; i++) {
            red[(quad*5+1+i)*4+wv] = paA[i];
            red[((quad+4)*5+1+i)*4+wv] = paB[i];
        }
    }
    __syncthreads();
    const int t = threadIdx.x;
    if (t < 40)
        atomicAdd(&accB[t], red[t*4+0]+red[t*4+1]+red[t*4+2]+red[t*4+3]);
}

// per-batch barrier over BPB blocks: monotone counter, release add + acquire poll.
__device__ __forceinline__ void gbar(unsigned* mybar, unsigned target) {
    __syncthreads();
    if (threadIdx.x == 0) {
        __hip_atomic_fetch_add(mybar, 1u, __ATOMIC_ACQ_REL, __HIP_MEMORY_SCOPE_AGENT);
        while (__hip_atomic_load(mybar, __ATOMIC_ACQUIRE, __HIP_MEMORY_SCOPE_AGENT) < target)
            __builtin_amdgcn_s_sleep(4);
    }
    __syncthreads();
}

// ---------------------------------------------------------------------------
// kPrep (parallel, 25 blocks): fp16 A-fragments. Per-layer frag ids:
//  0 M1=Wo@Wq  1 Cperm  2,3 Wv  4,5 Wk  6,7 Wq  8..11 FF1  12..15 FF2
// ids 96,97: W_emb K-tiles.  c2[l][od] = sum_c Wo[c][od]*b_r[c&3] + b_o[od].
// ---------------------------------------------------------------------------
__global__ __launch_bounds__(256) void kPrep(
    const float* __restrict__ Wqkv, const float* __restrict__ Wo,
    const float* __restrict__ Wr, const float* __restrict__ W1,
    const float* __restrict__ W2, const float* __restrict__ W_emb,
    const float* __restrict__ br, const float* __restrict__ bo,
    unsigned short* __restrict__ frag, float* __restrict__ c2)
{
    const int it = blockIdx.x*256 + (int)threadIdx.x;
    if (it < 98*64) {
        const int lane = it & 63, fid = it >> 6;
        const int m = lane & 15, q = lane >> 4;
        for (int j = 0; j < 4; j++) {
            const int k = q*4 + j;
            float w = 0.f;
            if (fid < 96) {
                const int layer = fid >> 4, f = fid & 15;
                const float* Wq_ = Wqkv + layer*1536;
                if (f == 0) {
                    for (int c = 0; c < 32; c++)
                        w += Wo[layer*512 + c*16 + m] * Wq_[k*96 + c];
                } else if (f == 1) {
                    const int h = q + ((j >= 2) ? 4 : 0), j2 = j & 1;
                    for (int d = 0; d < 4; d++)
                        w += Wo[layer*512 + (h*4+d)*16 + m] * Wr[layer*8 + j2*4 + d];
                } else if (f < 4)  w = Wq_[k*96 + 64 + (f-2)*16 + m];
                else if (f < 6)    w = Wq_[k*96 + 32 + (f-4)*16 + m];
                else if (f < 8)    w = Wq_[k*96 + (f-6)*16 + m];
                else if (f < 12)   w = W1[layer*1024 + k*64 + (f-8)*16 + m];
                else               w = W2[layer*1024 + ((f-12)*16 + k)*16 + m];
            } else {
                const int c = (fid-96)*16 + k;
                w = (c < NBOT) ? W_emb[c*16 + m] : 0.f;
            }
            frag[(size_t)it*4 + j] = h2u((_Float16)w);
        }
    }
    if (blockIdx.x == 0 && threadIdx.x < 96) {
        const int layer = threadIdx.x >> 4, od = threadIdx.x & 15;
        float s = bo[layer*16 + od];
        for (int c = 0; c < 32; c++)
            s += Wo[layer*512 + c*16 + od] * br[layer*4 + (c & 3)];
        c2[threadIdx.x] = s;
    }
}

// ---------------------------------------------------------------------------
// kMain: persistent kernel. X in 25 named f32x4 registers; Y recomputed.
// 12 per-batch barriers (2/layer, from the sequential q->k softmax reductions).
// amdgpu_num_vgpr(256): set the register budget directly (waves-per-eu
// requests were ignored by the backend; see header comment).
// ---------------------------------------------------------------------------
__global__
__attribute__((amdgpu_flat_work_group_size(PBLK, PBLK), amdgpu_num_vgpr(256)))
void kMain(
    const float* __restrict__ corr, const unsigned short* __restrict__ frag,
    const float* __restrict__ b_emb, const float* __restrict__ ln1_g,
    const float* __restrict__ ln1_b, const float* __restrict__ ln2_g,
    const float* __restrict__ ln2_b, const float* __restrict__ w_qlog,
    const float* __restrict__ w_klog, const float* __restrict__ c2,
    const float* __restrict__ b_ff1, const float* __restrict__ b_ff2,
    const float* __restrict__ W_out, const float* __restrict__ b_out,
    float* __restrict__ acc, unsigned* __restrict__ bar,
    float* __restrict__ out)
{
    __shared__ float red[160];

    const int lane = threadIdx.x & 63;
    const int col = lane & 15, quad = lane >> 4;
    const int gw = blockIdx.x*WPB + (int)(threadIdx.x >> 6);  // 0..2047
    const int b  = gw >> 7;                  // batch (block-uniform: 32 blks/batch)
    const int lw = gw & (WPBATCH-1);         // wave within batch
    const half4* F = (const half4*)frag;
    const float sgn = (col & 1) ? -1.f : 1.f;
    const f32x4 Z = {0,0,0,0};
    float* accQ = acc;
    float* accK = acc + NLAYERS*ACC_PER_LAYER;
    unsigned* mybar = bar + b*32;            // 128B-spaced per-batch counter
    const f32x4 wo4 = *(const f32x4*)(W_out + 4*quad);
    const float bout0 = b_out[0];

#define DECLX(i) f32x4 x##i;
    TILES(DECLX)
#undef DECLX

    // ---- embed: relu(corr)@W_emb + b_emb -> x0..x24; layer-0 q-partials
    {
        const half4 fE0 = F[96*64 + lane];
        const half4 fE1 = F[97*64 + lane];
        const half4 fQ0 = F[6*64 + lane];
        const half4 fQ1 = F[7*64 + lane];
        const f32x4 be4 = *(const f32x4*)(b_emb + 4*quad);
        const f32x4 g1  = *(const f32x4*)(ln1_g + 4*quad);
        const f32x4 b1  = *(const f32x4*)(ln1_b + 4*quad);
        const float wq0 = w_qlog[0], wq1 = w_qlog[1], wq2 = w_qlog[2], wq3 = w_qlog[3];
        // tile-invariant row pointers (8 rows this thread reads)
        const float* cr0 = corr + ((size_t)b*NBOT + (4*quad+0))*NTOK;
        const float* cr1 = corr + ((size_t)b*NBOT + (4*quad+1))*NTOK;
        const float* cr2 = corr + ((size_t)b*NBOT + (4*quad+2))*NTOK;
        const float* cr3 = corr + ((size_t)b*NBOT + (4*quad+3))*NTOK;
        const int d0 = (16+4*quad+0 < NBOT) ? 16+4*quad+0 : NBOT-1;
        const int d1 = (16+4*quad+1 < NBOT) ? 16+4*quad+1 : NBOT-1;
        const int d2 = (16+4*quad+2 < NBOT) ? 16+4*quad+2 : NBOT-1;
        const int d3 = (16+4*quad+3 < NBOT) ? 16+4*quad+3 : NBOT-1;
        const float* cs0 = corr + ((size_t)b*NBOT + d0)*NTOK;
        const float* cs1 = corr + ((size_t)b*NBOT + d1)*NTOK;
        const float* cs2 = corr + ((size_t)b*NBOT + d2)*NTOK;
        const float* cs3 = corr + ((size_t)b*NBOT + d3)*NTOK;
        float pwA = 0.f, pwB = 0.f;
        f32x4 paA = Z, paB = Z;

#define EMB(i) { \
        const int lt  = lw*TPWAVE + i; \
        const int ltc = (lt < NTILE) ? lt : (NTILE-1); \
        const int n0  = ltc*16; \
        const int valid = (lt < NTILE) && ((n0 + col) < NTOK); \
        const int nn = ((n0 + col) < NTOK) ? (n0 + col) : (NTOK - 1); \
        half4 ch0, ch1; \
        ch0[0] = (_Float16)fmaxf(cr0[nn], 0.f); \
        ch0[1] = (_Float16)fmaxf(cr1[nn], 0.f); \
        ch0[2] = (_Float16)fmaxf(cr2[nn], 0.f); \
        ch0[3] = (_Float16)fmaxf(cr3[nn], 0.f); \
        ch1[0] = (_Float16)fmaxf(cs0[nn], 0.f); \
        ch1[1] = (_Float16)fmaxf(cs1[nn], 0.f); \
        ch1[2] = (_Float16)fmaxf(cs2[nn], 0.f); \
        ch1[3] = (_Float16)fmaxf(cs3[nn], 0.f); \
        f32x4 xx = be4; \
        xx = MFMA(fE0, ch0, xx); \
        xx = MFMA(fE1, ch1, xx); \
        x##i = xx; \
        f32x4 y = ln16v(xx, g1, b1); \
        half4 yh = cvt4(y); \
        f32x4 q0 = MFMA(fQ0, yh, Z); \
        f32x4 q1 = MFMA(fQ1, yh, Z); \
        { float l = 0.5f*(q0[0]*wq0 + q0[1]*wq1 + q0[2]*wq2 + q0[3]*wq3); \
          float e = valid ? exp3(l) : 0.f; \
          pwA += e; paA += (e*sgn) * q0; } \
        { float l = 0.5f*(q1[0]*wq0 + q1[1]*wq1 + q1[2]*wq2 + q1[3]*wq3); \
          float e = valid ? exp3(l) : 0.f; \
          pwB += e; paB += (e*sgn) * q1; } }
        TILES(EMB)
#undef EMB
        accum_partials(pwA, paA, pwB, paB, red, accQ + b*40);
    }

    unsigned bstep = 1;
    for (int layer = 0; layer < NLAYERS; layer++) {
        const size_t fb = (size_t)layer*16*64;
        const int last = (layer == NLAYERS-1);
        const f32x4 g1c = *(const f32x4*)(ln1_g + layer*16 + 4*quad);
        const f32x4 b1c = *(const f32x4*)(ln1_b + layer*16 + 4*quad);

        gbar(mybar, BPB*bstep); bstep++;     // accQ[layer][b] complete

        // ---- phase B: k-projection + k-phase partials (Y recomputed from X)
        {
            const half4 fK0 = F[fb + 4*64 + lane];
            const half4 fK1 = F[fb + 5*64 + lane];
            f32x4 gqA, gqB; load_g(accQ + layer*ACC_PER_LAYER + b*40, quad, &gqA, &gqB);
            const float wk0 = w_klog[layer*2+0], wk1 = w_klog[layer*2+1];
            float pwA = 0.f, pwB = 0.f;
            f32x4 paA = Z, paB = Z;

#define PHB(i) { \
            const int lt = lw*TPWAVE + i; \
            const int valid = (lt < NTILE) && ((lt*16 + col) < NTOK); \
            f32x4 y = ln16v(x##i, g1c, b1c); \
            half4 yh = cvt4(y); \
            f32x4 k0 = MFMA(fK0, yh, Z); \
            f32x4 k1 = MFMA(fK1, yh, Z); \
            { float a0 = k0[0]*gqA[0] + k0[1]*gqA[1]; \
              float a1 = k0[2]*gqA[2] + k0[3]*gqA[3]; \
              float e = valid ? exp3(0.5f*(a0*wk0 + a1*wk1)) : 0.f; \
              pwA += e; paA += (e*sgn) * k0; } \
            { float a0 = k1[0]*gqB[0] + k1[1]*gqB[1]; \
              float a1 = k1[2]*gqB[2] + k1[3]*gqB[3]; \
              float e = valid ? exp3(0.5f*(a0*wk0 + a1*wk1)) : 0.f; \
              pwB += e; paB += (e*sgn) * k1; } }
            TILES(PHB)
#undef PHB
            accum_partials(pwA, paA, pwB, paB, red, accK + layer*ACC_PER_LAYER + b*40);
        }

        gbar(mybar, BPB*bstep); bstep++;     // accK[layer][b] complete

        // ---- phase C: attn delta -> xn -> LN2 -> FF -> xo; next-layer q-partials
        {
            const int nl = last ? layer : layer + 1;
            const size_t nb2 = (size_t)nl*16*64;
            const half4 fM1 = F[fb + 0*64 + lane];
            const half4 fCp = F[fb + 1*64 + lane];
            const half4 fV0 = F[fb + 2*64 + lane];
            const half4 fV1 = F[fb + 3*64 + lane];
            const half4 fF1_0 = F[fb + 8*64 + lane];
            const half4 fF1_1 = F[fb + 9*64 + lane];
            const half4 fF1_2 = F[fb + 10*64 + lane];
            const half4 fF1_3 = F[fb + 11*64 + lane];
            const half4 fF2_0 = F[fb + 12*64 + lane];
            const half4 fF2_1 = F[fb + 13*64 + lane];
            const half4 fF2_2 = F[fb + 14*64 + lane];
            const half4 fF2_3 = F[fb + 15*64 + lane];
            const half4 fQ0 = F[nb2 + 6*64 + lane];
            const half4 fQ1 = F[nb2 + 7*64 + lane];
            const f32x4 c2q  = *(const f32x4*)(c2 + layer*16 + 4*quad);
            const f32x4 g2   = *(const f32x4*)(ln2_g + layer*16 + 4*quad);
            const f32x4 b2   = *(const f32x4*)(ln2_b + layer*16 + 4*quad);
            const f32x4 g1n  = *(const f32x4*)(ln1_g + nl*16 + 4*quad);
            const f32x4 b1n  = *(const f32x4*)(ln1_b + nl*16 + 4*quad);
            const f32x4 bf2q = *(const f32x4*)(b_ff2 + layer*16 + 4*quad);
            const half4 bf1h0 = cvt4(*(const f32x4*)(b_ff1 + layer*64 +  0 + 4*quad));
            const half4 bf1h1 = cvt4(*(const f32x4*)(b_ff1 + layer*64 + 16 + 4*quad));
            const half4 bf1h2 = cvt4(*(const f32x4*)(b_ff1 + layer*64 + 32 + 4*quad));
            const half4 bf1h3 = cvt4(*(const f32x4*)(b_ff1 + layer*64 + 48 + 4*quad));
            f32x4 gkA, gkB; load_g(accK + layer*ACC_PER_LAYER + b*40, quad, &gkA, &gkB);
            const float wq0 = w_qlog[nl*4+0], wq1 = w_qlog[nl*4+1];
            const float wq2 = w_qlog[nl*4+2], wq3 = w_qlog[nl*4+3];
            float pwA = 0.f, pwB = 0.f;
            f32x4 paA = Z, paB = Z;

#define PHC(i) { \
            const int lt  = lw*TPWAVE + i; \
            const int ltc = (lt < NTILE) ? lt : (NTILE-1); \
            const int n0  = ltc*16; \
            const int valid = (lt < NTILE) && ((n0 + col) < NTOK); \
            f32x4 y1 = ln16v(x##i, g1c, b1c); \
            half4 yh = cvt4(y1); \
            f32x4 d = c2q; \
            d = MFMA(fM1, yh, d); \
            f32x4 v0 = MFMA(fV0, yh, Z); \
            f32x4 v1 = MFMA(fV1, yh, Z); \
            f32x4 u; \
            u[0] = v0[0]*gkA[0] + v0[1]*gkA[1]; \
            u[1] = v0[2]*gkA[2] + v0[3]*gkA[3]; \
            u[2] = v1[0]*gkB[0] + v1[1]*gkB[1]; \
            u[3] = v1[2]*gkB[2] + v1[3]*gkB[3]; \
            half4 uh = cvt4(u); \
            d = MFMA(fCp, uh, d); \
            f32x4 xn = x##i + d; \
            f32x4 y2 = ln16v(xn, g2, b2); \
            half4 y2h = cvt4(y2); \
            f32x4 z0 = MFMA(fF1_0, y2h, Z); \
            f32x4 z1 = MFMA(fF1_1, y2h, Z); \
            f32x4 z2 = MFMA(fF1_2, y2h, Z); \
            f32x4 z3 = MFMA(fF1_3, y2h, Z); \
            half4 h0 = gelu4(cvt4(z0) + bf1h0); \
            half4 h1 = gelu4(cvt4(z1) + bf1h1); \
            half4 h2 = gelu4(cvt4(z2) + bf1h2); \
            half4 h3 = gelu4(cvt4(z3) + bf1h3); \
            f32x4 xo = xn + bf2q; \
            xo = MFMA(fF2_0, h0, xo); \
            xo = MFMA(fF2_1, h1, xo); \
            f32x4 xb = MFMA(fF2_2, h2, Z); \
            xb = MFMA(fF2_3, h3, xb); \
            xo = xo + xb; \
            x##i = xo; \
            if (!last) { \
                f32x4 yn = ln16v(xo, g1n, b1n); \
                half4 ynh = cvt4(yn); \
                f32x4 q0 = MFMA(fQ0, ynh, Z); \
                f32x4 q1 = MFMA(fQ1, ynh, Z); \
                { float l = 0.5f*(q0[0]*wq0 + q0[1]*wq1 + q0[2]*wq2 + q0[3]*wq3); \
                  float e = valid ? exp3(l) : 0.f; \
                  pwA += e; paA += (e*sgn) * q0; } \
                { float l = 0.5f*(q1[0]*wq0 + q1[1]*wq1 + q1[2]*wq2 + q1[3]*wq3); \
                  float e = valid ? exp3(l) : 0.f; \
                  pwB += e; paB += (e*sgn) * q1; } \
            } else { \
                float s = xo[0]*wo4[0] + xo[1]*wo4[1] + xo[2]*wo4[2] + xo[3]*wo4[3]; \
                s += __shfl_xor(s, 16); s += __shfl_xor(s, 32); \
                if (quad == 0 && valid) out[(size_t)b*NTOK + n0 + col] = s + bout0; \
            } }
            TILES(PHC)
#undef PHC
            if (!last)
                accum_partials(pwA, paA, pwB, paB, red, accQ + (layer+1)*ACC_PER_LAYER + b*40);
        }
    }
}

extern "C" void kernel_launch(void* const* d_in, const int* in_sizes, int n_in,
                              void* d_out, int out_size, void* d_ws, size_t ws_size,
                              hipStream_t stream) {
    const float* corr  = (const float*)d_in[0];
    const float* W_emb = (const float*)d_in[1];
    const float* b_emb = (const float*)d_in[2];
    const float* ln1_g = (const float*)d_in[3];
    const float* ln1_b = (const float*)d_in[4];
    const float* W_qkv = (const float*)d_in[5];
    const float* w_qlog= (const float*)d_in[6];
    const float* w_klog= (const float*)d_in[7];
    const float* W_r   = (const float*)d_in[8];
    const float* b_r   = (const float*)d_in[9];
    const float* W_o   = (const float*)d_in[10];
    const float* b_o   = (const float*)d_in[11];
    const float* ln2_g = (const float*)d_in[12];
    const float* ln2_b = (const float*)d_in[13];
    const float* W_ff1 = (const float*)d_in[14];
    const float* b_ff1 = (const float*)d_in[15];
    const float* W_ff2 = (const float*)d_in[16];
    const float* b_ff2 = (const float*)d_in[17];
    const float* W_out = (const float*)d_in[18];
    const float* b_out = (const float*)d_in[19];

    float* acc = (float*)d_ws;
    unsigned* bar = (unsigned*)((char*)d_ws + BAR_OFF);
    unsigned short* frag = (unsigned short*)((char*)d_ws + FRAG_OFF);
    float* c2 = (float*)((char*)d_ws + C2_OFF);

    // zero acc (30720 B) + 16 per-batch barrier counters (2048 B) in one memset
    hipMemsetAsync(d_ws, 0, 32768, stream);
    kPrep<<<25, 256, 0, stream>>>(W_qkv, W_o, W_r, W_ff1, W_ff2, W_emb, b_r, b_o,
                                  frag, c2);

    kMain<<<dim3(PGRID), dim3(PBLK), 0, stream>>>(
        corr, frag, b_emb, ln1_g, ln1_b, ln2_g, ln2_b, w_qlog, w_klog, c2,
        b_ff1, b_ff2, W_out, b_out, acc, bar, (float*)d_out);
}